// Round 1
// baseline (1115.840 us; speedup 1.0000x reference)
//
#include <hip/hip_runtime.h>
#include <hip/hip_bf16.h>
#include <math.h>

// Problem dims (fixed by reference)
#define B_SZ 256
#define P_SZ 256
#define LD   128   // L_DIM (evolving part)
#define ZD   256   // Z_DIM
#define HD   256   // H_DIM
#define NSTEP 8            // RK4 macro steps over [0,1]
#define SPAN (P_SZ/NSTEP)  // fine intervals per macro step = 32
#define RR   4             // batch rows per block in ODE kernel
#define TT   16            // points per block in decode kernel

__device__ __forceinline__ float fast_tanh(float v) {
  // tanh(x) = sign(x) * (1 - 2/(e^{2|x|}+1)) ; rel err ~1e-6
  float e = __expf(2.0f * fabsf(v));
  float r = 1.0f - 2.0f / (e + 1.0f);
  return copysignf(r, v);
}

// ---------------------------------------------------------------------------
// Kernel 1: RK4 integrate the latent ODE for RR batch rows per block,
// Hermite dense output -> latent[b][p][k] (bf16) for p = 0..255 (t=(p+1)/256).
// ---------------------------------------------------------------------------
__global__ __launch_bounds__(256) void ode_kernel(
    const float* __restrict__ x, const float* __restrict__ z,
    const float* __restrict__ x0,
    const float* __restrict__ W1, const float* __restrict__ b1,
    const float* __restrict__ W2, const float* __restrict__ b2,
    const float* __restrict__ W3, const float* __restrict__ b3,
    __hip_bfloat16* __restrict__ latent)
{
  __shared__ float times[P_SZ + 1];
  __shared__ float vL[RR][LD];     // evolving state
  __shared__ float vNew[RR][LD];   // next state
  __shared__ float zf[RR][LD];     // frozen z[:,128:]
  __shared__ float inbuf[RR][ZD];  // layer-1 input (v part; time handled separately)
  __shared__ float h1[RR][HD];
  __shared__ float h2[RR][HD];
  __shared__ float kb[4][RR][LD];  // RK4 stages

  const int tid = threadIdx.x;
  const int b0  = blockIdx.x * RR;

  for (int m = tid; m <= P_SZ; m += 256) times[m] = (m == 0) ? x0[0] : x[m - 1];
  for (int idx = tid; idx < RR * LD; idx += 256) {
    int r = idx >> 7, k = idx & (LD - 1);
    vL[r][k] = z[(b0 + r) * ZD + k];
    zf[r][k] = z[(b0 + r) * ZD + LD + k];
    kb[0][r][k] = 0.f; kb[1][r][k] = 0.f; kb[2][r][k] = 0.f; kb[3][r][k] = 0.f;
  }
  __syncthreads();

  const float b1j = b1[tid];
  const float b2j = b2[tid];
  const float b3j = b3[tid & (LD - 1)];

  // kout[r][j] = f_L(t, vsrc + c*kin)   (all arrays in LDS)
  auto eval_f = [&](float t, float (*vsrc)[LD], float (*kin)[LD], float c,
                    float (*kout)[LD]) {
    // build input vector (v = [vL', zf]); time appended analytically below
    for (int idx = tid; idx < RR * ZD; idx += 256) {
      int r = idx >> 8, i = idx & (ZD - 1);
      inbuf[r][i] = (i < LD) ? (vsrc[r][i] + c * kin[r][i]) : zf[r][i - LD];
    }
    __syncthreads();
    // ---- layer 1: 257 -> 256, tanh ----
    {
      float a0 = b1j, a1 = b1j, a2 = b1j, a3 = b1j;
      for (int i = 0; i < ZD; i += 4) {
        float w0 = W1[(i + 0) * HD + tid];
        float w1 = W1[(i + 1) * HD + tid];
        float w2 = W1[(i + 2) * HD + tid];
        float w3 = W1[(i + 3) * HD + tid];
        float4 v0 = *(const float4*)&inbuf[0][i];
        float4 v1 = *(const float4*)&inbuf[1][i];
        float4 v2 = *(const float4*)&inbuf[2][i];
        float4 v3 = *(const float4*)&inbuf[3][i];
        a0 += v0.x * w0 + v0.y * w1 + v0.z * w2 + v0.w * w3;
        a1 += v1.x * w0 + v1.y * w1 + v1.z * w2 + v1.w * w3;
        a2 += v2.x * w0 + v2.y * w1 + v2.z * w2 + v2.w * w3;
        a3 += v3.x * w0 + v3.y * w1 + v3.z * w2 + v3.w * w3;
      }
      float wt = W1[ZD * HD + tid];   // time row (row 256)
      a0 += t * wt; a1 += t * wt; a2 += t * wt; a3 += t * wt;
      h1[0][tid] = fast_tanh(a0);
      h1[1][tid] = fast_tanh(a1);
      h1[2][tid] = fast_tanh(a2);
      h1[3][tid] = fast_tanh(a3);
    }
    __syncthreads();
    // ---- layer 2: 256 -> 256, tanh ----
    {
      float a0 = b2j, a1 = b2j, a2 = b2j, a3 = b2j;
      for (int i = 0; i < HD; i += 4) {
        float w0 = W2[(i + 0) * HD + tid];
        float w1 = W2[(i + 1) * HD + tid];
        float w2 = W2[(i + 2) * HD + tid];
        float w3 = W2[(i + 3) * HD + tid];
        float4 v0 = *(const float4*)&h1[0][i];
        float4 v1 = *(const float4*)&h1[1][i];
        float4 v2 = *(const float4*)&h1[2][i];
        float4 v3 = *(const float4*)&h1[3][i];
        a0 += v0.x * w0 + v0.y * w1 + v0.z * w2 + v0.w * w3;
        a1 += v1.x * w0 + v1.y * w1 + v1.z * w2 + v1.w * w3;
        a2 += v2.x * w0 + v2.y * w1 + v2.z * w2 + v2.w * w3;
        a3 += v3.x * w0 + v3.y * w1 + v3.z * w2 + v3.w * w3;
      }
      h2[0][tid] = fast_tanh(a0);
      h2[1][tid] = fast_tanh(a1);
      h2[2][tid] = fast_tanh(a2);
      h2[3][tid] = fast_tanh(a3);
    }
    __syncthreads();
    // ---- layer 3: 256 -> 128 (no act). threads split: half -> rows {0,1} / {2,3}
    {
      int half = tid >> 7, jj = tid & (LD - 1);
      float a0 = b3j, a1 = b3j;
      const float* r0 = h2[half * 2 + 0];
      const float* r1 = h2[half * 2 + 1];
      for (int i = 0; i < HD; i += 4) {
        float w0 = W3[(i + 0) * LD + jj];
        float w1 = W3[(i + 1) * LD + jj];
        float w2 = W3[(i + 2) * LD + jj];
        float w3 = W3[(i + 3) * LD + jj];
        float4 v0 = *(const float4*)&r0[i];
        float4 v1 = *(const float4*)&r1[i];
        a0 += v0.x * w0 + v0.y * w1 + v0.z * w2 + v0.w * w3;
        a1 += v1.x * w0 + v1.y * w1 + v1.z * w2 + v1.w * w3;
      }
      kout[half * 2 + 0][jj] = a0;
      kout[half * 2 + 1][jj] = a1;
    }
    __syncthreads();
  };

  // k1 at t=0
  eval_f(times[0], vL, kb[0], 0.f, kb[0]);

  for (int n = 0; n < NSTEP; n++) {
    float t0 = times[n * SPAN], t1 = times[(n + 1) * SPAN];
    float H = t1 - t0, tm = t0 + 0.5f * H;
    eval_f(tm, vL, kb[0], 0.5f * H, kb[1]);   // k2
    eval_f(tm, vL, kb[1], 0.5f * H, kb[2]);   // k3
    eval_f(t1, vL, kb[2], H,        kb[3]);   // k4
    for (int idx = tid; idx < RR * LD; idx += 256) {
      int r = idx >> 7, k = idx & (LD - 1);
      vNew[r][k] = vL[r][k] + (H / 6.0f) *
          (kb[0][r][k] + 2.f * kb[1][r][k] + 2.f * kb[2][r][k] + kb[3][r][k]);
    }
    __syncthreads();
    eval_f(t1, vNew, kb[0], 0.f, kb[1]);      // k1 of next step == f1 for Hermite
    // cubic-Hermite dense output for the SPAN fine points in (t0, t1]
    float invH = 1.0f / H;
    for (int idx = tid; idx < SPAN * RR * LD; idx += 256) {
      int m_i = idx >> 9;          // / (RR*LD)
      int rem = idx & 511;
      int r = rem >> 7, k = rem & (LD - 1);
      int m = n * SPAN + 1 + m_i;
      float s  = (times[m] - t0) * invH;
      float s2 = s * s, s3 = s2 * s;
      float h00 = 2.f * s3 - 3.f * s2 + 1.f;
      float h10 = s3 - 2.f * s2 + s;
      float h01 = 3.f * s2 - 2.f * s3;
      float h11 = s3 - s2;
      float val = h00 * vL[r][k] + (h10 * H) * kb[0][r][k]
                + h01 * vNew[r][k] + (h11 * H) * kb[1][r][k];
      latent[((size_t)(b0 + r) * P_SZ + (m - 1)) * LD + k] = __float2bfloat16(val);
    }
    __syncthreads();
    for (int idx = tid; idx < RR * LD; idx += 256) {
      int r = idx >> 7, k = idx & (LD - 1);
      vL[r][k]    = vNew[r][k];
      kb[0][r][k] = kb[1][r][k];
    }
    __syncthreads();
  }
}

// ---------------------------------------------------------------------------
// Kernel 2: zh[b][j] = bh[j] + sum_k z[b][128+k] * Wh[(129+k)][j]  (b-only part)
// ---------------------------------------------------------------------------
__global__ __launch_bounds__(256) void zh_kernel(
    const float* __restrict__ z, const float* __restrict__ Wh,
    const float* __restrict__ bh, float* __restrict__ zh)
{
  const int b = blockIdx.x, j = threadIdx.x;
  __shared__ float zr[LD];
  if (j < LD) zr[j] = z[b * ZD + LD + j];
  __syncthreads();
  float acc = bh[j];
  for (int k = 0; k < LD; k += 4) {
    float4 zv = *(const float4*)&zr[k];
    acc += zv.x * Wh[(LD + 1 + k) * HD + j] + zv.y * Wh[(LD + 2 + k) * HD + j]
         + zv.z * Wh[(LD + 3 + k) * HD + j] + zv.w * Wh[(LD + 4 + k) * HD + j];
  }
  zh[b * HD + j] = acc;
}

// ---------------------------------------------------------------------------
// Kernel 3: decode. pre = x*Wh[0] + latent@Wh[1:129] + zh ; hidden = relu(pre)
// mu = [latent,hidden]@Wmu + bmu ; sigma = 0.1 + 0.9*softplus([latent,hidden]@Wsig + bsig)
// ---------------------------------------------------------------------------
__global__ __launch_bounds__(256) void decode_kernel(
    const float* __restrict__ x, const __hip_bfloat16* __restrict__ latent,
    const float* __restrict__ zh, const float* __restrict__ Wh,
    const float* __restrict__ Wmu, const float* __restrict__ bmu,
    const float* __restrict__ Wsig, const float* __restrict__ bsig,
    float* __restrict__ out)
{
  const int b  = blockIdx.y;
  const int p0 = blockIdx.x * TT;
  const int j  = threadIdx.x;
  __shared__ float lat[TT][LD];
  __shared__ float xv[TT];
  __shared__ float zhs[HD];
  __shared__ float red[TT][256];

  for (int idx = j; idx < TT * LD; idx += 256) {
    int t = idx >> 7, k = idx & (LD - 1);
    lat[t][k] = __bfloat162float(latent[((size_t)b * P_SZ + p0 + t) * LD + k]);
  }
  if (j < TT) xv[j] = x[b * P_SZ + p0 + j];
  zhs[j] = zh[b * HD + j];
  __syncthreads();

  float acc[TT];
  float wh0 = Wh[j];        // Wh row 0 (x input)
  float zhj = zhs[j];
#pragma unroll
  for (int t = 0; t < TT; t++) acc[t] = zhj + xv[t] * wh0;

  for (int k = 0; k < LD; k += 4) {
    float w0 = Wh[(1 + k) * HD + j];
    float w1 = Wh[(2 + k) * HD + j];
    float w2 = Wh[(3 + k) * HD + j];
    float w3 = Wh[(4 + k) * HD + j];
#pragma unroll
    for (int t = 0; t < TT; t++) {
      float4 lv = *(const float4*)&lat[t][k];
      acc[t] += lv.x * w0 + lv.y * w1 + lv.z * w2 + lv.w * w3;
    }
  }
#pragma unroll
  for (int t = 0; t < TT; t++) acc[t] = fmaxf(acc[t], 0.f);

  // ---- mu ----
  {
    float wmh = Wmu[LD + j];
    float wml = (j < LD) ? Wmu[j] : 0.f;
#pragma unroll
    for (int t = 0; t < TT; t++) {
      float v = acc[t] * wmh;
      if (j < LD) v += lat[t][j] * wml;
      red[t][j] = v;
    }
    __syncthreads();
    for (int s = 128; s > 0; s >>= 1) {
      if (j < s) {
#pragma unroll
        for (int t = 0; t < TT; t++) red[t][j] += red[t][j + s];
      }
      __syncthreads();
    }
    if (j < TT) out[(size_t)b * P_SZ + p0 + j] = red[j][0] + bmu[0];
    __syncthreads();
  }
  // ---- sigma ----
  {
    float wsh = Wsig[LD + j];
    float wsl = (j < LD) ? Wsig[j] : 0.f;
#pragma unroll
    for (int t = 0; t < TT; t++) {
      float v = acc[t] * wsh;
      if (j < LD) v += lat[t][j] * wsl;
      red[t][j] = v;
    }
    __syncthreads();
    for (int s = 128; s > 0; s >>= 1) {
      if (j < s) {
#pragma unroll
        for (int t = 0; t < TT; t++) red[t][j] += red[t][j + s];
      }
      __syncthreads();
    }
    if (j < TT) {
      float sv = red[j][0] + bsig[0];
      float sp = (sv > 20.f) ? sv : log1pf(__expf(sv));
      out[(size_t)B_SZ * P_SZ + b * P_SZ + p0 + j] = 0.1f + 0.9f * sp;
    }
  }
}

// ---------------------------------------------------------------------------
extern "C" void kernel_launch(void* const* d_in, const int* in_sizes, int n_in,
                              void* d_out, int out_size, void* d_ws, size_t ws_size,
                              hipStream_t stream) {
  const float* x    = (const float*)d_in[0];
  const float* z    = (const float*)d_in[1];
  const float* x0   = (const float*)d_in[2];
  const float* W1   = (const float*)d_in[3];
  const float* b1   = (const float*)d_in[4];
  const float* W2   = (const float*)d_in[5];
  const float* b2   = (const float*)d_in[6];
  const float* W3   = (const float*)d_in[7];
  const float* b3   = (const float*)d_in[8];
  const float* Wh   = (const float*)d_in[9];
  const float* bh   = (const float*)d_in[10];
  const float* Wmu  = (const float*)d_in[11];
  const float* bmu  = (const float*)d_in[12];
  const float* Wsig = (const float*)d_in[13];
  const float* bsig = (const float*)d_in[14];
  float* out = (float*)d_out;

  __hip_bfloat16* latent = (__hip_bfloat16*)d_ws;                       // 16.78 MB
  float* zh = (float*)((char*)d_ws + (size_t)B_SZ * P_SZ * LD * sizeof(__hip_bfloat16));

  zh_kernel<<<dim3(B_SZ), dim3(256), 0, stream>>>(z, Wh, bh, zh);
  ode_kernel<<<dim3(B_SZ / RR), dim3(256), 0, stream>>>(
      x, z, x0, W1, b1, W2, b2, W3, b3, latent);
  decode_kernel<<<dim3(P_SZ / TT, B_SZ), dim3(256), 0, stream>>>(
      x, latent, zh, Wh, Wmu, bmu, Wsig, bsig, out);
}

// Round 2
// 994.858 us; speedup vs baseline: 1.1216x; 1.1216x over previous
//
#include <hip/hip_runtime.h>
#include <hip/hip_bf16.h>
#include <math.h>

// Problem dims (fixed by reference)
#define B_SZ 256
#define P_SZ 256
#define LD   128   // L_DIM (evolving part)
#define ZD   256   // Z_DIM
#define HD   256   // H_DIM
#define NSTEP 8            // RK4 macro steps over [0,1]
#define SPAN (P_SZ/NSTEP)  // fine intervals per macro step = 32
#define TT   16            // points per block in decode kernel

__device__ __forceinline__ float fast_tanh(float v) {
  float e = __expf(2.0f * fabsf(v));
  float r = 1.0f - 2.0f / (e + 1.0f);
  return copysignf(r, v);
}

__device__ __forceinline__ unsigned int bf_bits(float f) {
  unsigned int u = __float_as_uint(f);
  return (u + 0x7fffu + ((u >> 16) & 1u)) >> 16;   // RNE
}

// dot of 64 contiguous k against packed bf16 weights (k-pairs in uint2)
__device__ __forceinline__ float dot64(const uint2* __restrict__ Wq, int ldq,
                                       int u, int kbase,
                                       const float* __restrict__ vin) {
  float acc = 0.f;
#pragma unroll
  for (int k = kbase; k < kbase + 64; k += 4) {
    uint2 w = Wq[(k >> 2) * ldq + u];
    float4 vv = *(const float4*)&vin[k];
    acc += vv.x * __uint_as_float(w.x << 16);
    acc += vv.y * __uint_as_float(w.x & 0xffff0000u);
    acc += vv.z * __uint_as_float(w.y << 16);
    acc += vv.w * __uint_as_float(w.y & 0xffff0000u);
  }
  return acc;
}

// ---------------------------------------------------------------------------
// Prep: pack W1[0:128], W2, W3 into bf16 k-pair uint2 layout.
// W1q: (k>>2)*256+u for k in [0,128)    -> 8192 uint2
// W2q: (k>>2)*256+u for k in [0,256)    -> 16384 uint2
// W3q: (k>>2)*128+u for k in [0,256)    -> 8192 uint2
// ---------------------------------------------------------------------------
__global__ __launch_bounds__(256) void pack_kernel(
    const float* __restrict__ W1, const float* __restrict__ W2,
    const float* __restrict__ W3,
    uint2* __restrict__ W1q, uint2* __restrict__ W2q, uint2* __restrict__ W3q)
{
  int idx = blockIdx.x * 256 + threadIdx.x;
  if (idx < 8192) {
    int r = idx >> 8, u = idx & 255, k = r * 4;
    uint2 o;
    o.x = bf_bits(W1[(k + 0) * HD + u]) | (bf_bits(W1[(k + 1) * HD + u]) << 16);
    o.y = bf_bits(W1[(k + 2) * HD + u]) | (bf_bits(W1[(k + 3) * HD + u]) << 16);
    W1q[idx] = o;
  } else if (idx < 24576) {
    int i = idx - 8192;
    int r = i >> 8, u = i & 255, k = r * 4;
    uint2 o;
    o.x = bf_bits(W2[(k + 0) * HD + u]) | (bf_bits(W2[(k + 1) * HD + u]) << 16);
    o.y = bf_bits(W2[(k + 2) * HD + u]) | (bf_bits(W2[(k + 3) * HD + u]) << 16);
    W2q[i] = o;
  } else {
    int i = idx - 24576;
    int r = i >> 7, u = i & 127, k = r * 4;
    uint2 o;
    o.x = bf_bits(W3[(k + 0) * LD + u]) | (bf_bits(W3[(k + 1) * LD + u]) << 16);
    o.y = bf_bits(W3[(k + 2) * LD + u]) | (bf_bits(W3[(k + 3) * LD + u]) << 16);
    W3q[i] = o;
  }
}

// ---------------------------------------------------------------------------
// Kernel 1: one batch row per block, 512 threads (split-K partials).
// RK4 + cubic-Hermite dense output -> latent (bf16).
// ---------------------------------------------------------------------------
__global__ __launch_bounds__(512) void ode_kernel(
    const float* __restrict__ x, const float* __restrict__ z,
    const float* __restrict__ x0,
    const float* __restrict__ W1, const float* __restrict__ b1,
    const float* __restrict__ b2, const float* __restrict__ b3,
    const uint2* __restrict__ W1q, const uint2* __restrict__ W2q,
    const uint2* __restrict__ W3q,
    __hip_bfloat16* __restrict__ latent)
{
  __shared__ float times[P_SZ + 1];
  __shared__ float vL[LD], vNew[LD], vin[LD], zf[LD];
  __shared__ float kb0[LD], kb1[LD], kb2[LD], kb3[LD];
  __shared__ float c1[HD], h1s[HD], h2s[HD];
  __shared__ float part[4][HD];

  const int tid = threadIdx.x;
  const int b   = blockIdx.x;
  const int u8  = tid & 255;   // hidden-unit index (layers 1/2)
  const int h2i = tid >> 8;    // split-K half (layers 1/2)
  const int u7  = tid & 127;   // output index (layer 3)
  const int s4  = tid >> 7;    // split-K quarter (layer 3)

  // registers for biases / time column
  const float b2r = b2[u8];
  const float b3r = b3[u7];
  const float w1t = W1[ZD * HD + u8];   // W1 row 256 (time), fp32

  for (int m = tid; m <= P_SZ; m += 512) times[m] = (m == 0) ? x0[0] : x[m - 1];
  if (tid < LD) {
    vL[tid] = z[b * ZD + tid];
    zf[tid] = z[b * ZD + LD + tid];
    kb0[tid] = 0.f; kb1[tid] = 0.f; kb2[tid] = 0.f; kb3[tid] = 0.f;
  }
  __syncthreads();

  // c1[u] = b1[u] + zf . W1[128..255][u]  (fp32 weights for accuracy)
  {
    float acc = 0.f;
    int kb = h2i * 64;
#pragma unroll 8
    for (int k = kb; k < kb + 64; k += 4) {
      float4 zv = *(const float4*)&zf[k];
      acc += zv.x * W1[(LD + k + 0) * HD + u8];
      acc += zv.y * W1[(LD + k + 1) * HD + u8];
      acc += zv.z * W1[(LD + k + 2) * HD + u8];
      acc += zv.w * W1[(LD + k + 3) * HD + u8];
    }
    part[h2i][u8] = acc;
    __syncthreads();
    if (tid < HD) c1[tid] = b1[tid] + part[0][tid] + part[1][tid];
    __syncthreads();
  }

  // kout = f_L(t, vsrc + c*kin)
  auto eval_f = [&](float t, float* vsrc, float* kin, float c, float* kout) {
    if (tid < LD) vin[tid] = vsrc[tid] + c * kin[tid];
    __syncthreads();
    // layer 1 (K = 128 vL + time; zf folded into c1)
    {
      float acc = dot64(W1q, HD, u8, h2i * 64, vin);
      acc += (h2i == 0) ? c1[u8] : t * w1t;
      part[h2i][u8] = acc;
    }
    __syncthreads();
    if (tid < HD) h1s[tid] = fast_tanh(part[0][tid] + part[1][tid]);
    __syncthreads();
    // layer 2 (K = 256)
    {
      float acc = dot64(W2q, HD, u8, h2i * 128, h1s)
                + dot64(W2q, HD, u8, h2i * 128 + 64, h1s);
      part[h2i][u8] = acc;
    }
    __syncthreads();
    if (tid < HD) h2s[tid] = fast_tanh(part[0][tid] + part[1][tid] + b2r);
    __syncthreads();
    // layer 3 (K = 256 -> 128 outputs, split-K 4)
    part[s4][u7] = dot64(W3q, LD, u7, s4 * 64, h2s);
    __syncthreads();
    if (tid < LD)
      kout[tid] = b3r + part[0][tid] + part[1][tid] + part[2][tid] + part[3][tid];
    __syncthreads();
  };

  eval_f(times[0], vL, kb0, 0.f, kb0);   // k1 at t=0 (kb0 zero-initialized)

  for (int n = 0; n < NSTEP; n++) {
    float t0 = times[n * SPAN], t1 = times[(n + 1) * SPAN];
    float H = t1 - t0, tm = t0 + 0.5f * H;
    eval_f(tm, vL, kb0, 0.5f * H, kb1);   // k2
    eval_f(tm, vL, kb1, 0.5f * H, kb2);   // k3
    eval_f(t1, vL, kb2, H,        kb3);   // k4
    if (tid < LD)
      vNew[tid] = vL[tid] + (H / 6.0f) *
          (kb0[tid] + 2.f * kb1[tid] + 2.f * kb2[tid] + kb3[tid]);
    __syncthreads();
    eval_f(t1, vNew, kb0, 0.f, kb1);      // f at t1 (Hermite right slope)

    float invH = 1.0f / H;
    for (int idx = tid; idx < SPAN * LD; idx += 512) {
      int m_i = idx >> 7, k = idx & (LD - 1);
      int m = n * SPAN + 1 + m_i;
      float s  = (times[m] - t0) * invH;
      float s2 = s * s, s3 = s2 * s;
      float h00 = 2.f * s3 - 3.f * s2 + 1.f;
      float h10 = s3 - 2.f * s2 + s;
      float h01 = 3.f * s2 - 2.f * s3;
      float h11 = s3 - s2;
      float val = h00 * vL[k] + (h10 * H) * kb0[k]
                + h01 * vNew[k] + (h11 * H) * kb1[k];
      latent[((size_t)b * P_SZ + (m - 1)) * LD + k] = __float2bfloat16(val);
    }
    __syncthreads();
    if (tid < LD) { vL[tid] = vNew[tid]; kb0[tid] = kb1[tid]; }
    __syncthreads();
  }
}

// ---------------------------------------------------------------------------
// Kernel 2: zh[b][j] = bh[j] + sum_k z[b][128+k] * Wh[(129+k)][j]
// ---------------------------------------------------------------------------
__global__ __launch_bounds__(256) void zh_kernel(
    const float* __restrict__ z, const float* __restrict__ Wh,
    const float* __restrict__ bh, float* __restrict__ zh)
{
  const int b = blockIdx.x, j = threadIdx.x;
  __shared__ float zr[LD];
  if (j < LD) zr[j] = z[b * ZD + LD + j];
  __syncthreads();
  float acc = bh[j];
#pragma unroll 8
  for (int k = 0; k < LD; k += 4) {
    float4 zv = *(const float4*)&zr[k];
    acc += zv.x * Wh[(LD + 1 + k) * HD + j] + zv.y * Wh[(LD + 2 + k) * HD + j]
         + zv.z * Wh[(LD + 3 + k) * HD + j] + zv.w * Wh[(LD + 4 + k) * HD + j];
  }
  zh[b * HD + j] = acc;
}

// ---------------------------------------------------------------------------
// Kernel 3: decode with wave-local reductions.
// ---------------------------------------------------------------------------
__global__ __launch_bounds__(256) void decode_kernel(
    const float* __restrict__ x, const __hip_bfloat16* __restrict__ latent,
    const float* __restrict__ zh, const float* __restrict__ Wh,
    const float* __restrict__ Wmu, const float* __restrict__ bmu,
    const float* __restrict__ Wsig, const float* __restrict__ bsig,
    float* __restrict__ out)
{
  const int b  = blockIdx.y;
  const int p0 = blockIdx.x * TT;
  const int j  = threadIdx.x;
  __shared__ float lat[TT][LD];
  __shared__ float hid[TT][HD];
  __shared__ float xv[TT];
  __shared__ float zhs[HD];

  // latent bf16 -> LDS fp32 (dword = 2 bf16)
  {
    const unsigned int* lp = (const unsigned int*)latent;
    for (int idx = j; idx < TT * LD / 2; idx += 256) {
      int t = idx >> 6, kk = (idx & 63) * 2;
      unsigned int ld2 = lp[((size_t)b * P_SZ + p0 + t) * (LD / 2) + (idx & 63)];
      lat[t][kk]     = __uint_as_float(ld2 << 16);
      lat[t][kk + 1] = __uint_as_float(ld2 & 0xffff0000u);
    }
  }
  if (j < TT) xv[j] = x[b * P_SZ + p0 + j];
  zhs[j] = zh[b * HD + j];
  __syncthreads();

  // phase 1: hidden[t][j] = relu(x*Wh0 + latent@Wh[1:129] + zh)
  float acc[TT];
  float wh0 = Wh[j];
  float zhj = zhs[j];
#pragma unroll
  for (int t = 0; t < TT; t++) acc[t] = zhj + xv[t] * wh0;

  for (int k = 0; k < LD; k += 4) {
    float w0 = Wh[(1 + k) * HD + j];
    float w1 = Wh[(2 + k) * HD + j];
    float w2 = Wh[(3 + k) * HD + j];
    float w3 = Wh[(4 + k) * HD + j];
#pragma unroll
    for (int t = 0; t < TT; t++) {
      float4 lv = *(const float4*)&lat[t][k];
      acc[t] += lv.x * w0 + lv.y * w1 + lv.z * w2 + lv.w * w3;
    }
  }
#pragma unroll
  for (int t = 0; t < TT; t++) hid[t][j] = fmaxf(acc[t], 0.f);
  __syncthreads();

  // phase 2: each wave handles 4 points; lanewise partial over 384-dim, shfl reduce
  const int w = j >> 6, l = j & 63;
  float wmu_h[4], wsg_h[4], wmu_l[2], wsg_l[2];
#pragma unroll
  for (int c = 0; c < 4; c++) {
    wmu_h[c] = Wmu[LD + l + 64 * c];
    wsg_h[c] = Wsig[LD + l + 64 * c];
  }
#pragma unroll
  for (int c = 0; c < 2; c++) {
    wmu_l[c] = Wmu[l + 64 * c];
    wsg_l[c] = Wsig[l + 64 * c];
  }
  const float bmu0 = bmu[0], bsg0 = bsig[0];

#pragma unroll
  for (int tt = 0; tt < 4; tt++) {
    int t = w * 4 + tt;
    float m = 0.f, sg = 0.f;
#pragma unroll
    for (int c = 0; c < 4; c++) {
      float hv = hid[t][l + 64 * c];
      m += hv * wmu_h[c]; sg += hv * wsg_h[c];
    }
#pragma unroll
    for (int c = 0; c < 2; c++) {
      float lv = lat[t][l + 64 * c];
      m += lv * wmu_l[c]; sg += lv * wsg_l[c];
    }
#pragma unroll
    for (int off = 32; off > 0; off >>= 1) {
      m  += __shfl_down(m, off);
      sg += __shfl_down(sg, off);
    }
    if (l == 0) {
      out[(size_t)b * P_SZ + p0 + t] = m + bmu0;
      float sv = sg + bsg0;
      float sp = (sv > 20.f) ? sv : log1pf(__expf(sv));
      out[(size_t)B_SZ * P_SZ + b * P_SZ + p0 + t] = 0.1f + 0.9f * sp;
    }
  }
}

// ---------------------------------------------------------------------------
extern "C" void kernel_launch(void* const* d_in, const int* in_sizes, int n_in,
                              void* d_out, int out_size, void* d_ws, size_t ws_size,
                              hipStream_t stream) {
  const float* x    = (const float*)d_in[0];
  const float* z    = (const float*)d_in[1];
  const float* x0   = (const float*)d_in[2];
  const float* W1   = (const float*)d_in[3];
  const float* b1   = (const float*)d_in[4];
  const float* W2   = (const float*)d_in[5];
  const float* b2   = (const float*)d_in[6];
  const float* W3   = (const float*)d_in[7];
  const float* b3   = (const float*)d_in[8];
  const float* Wh   = (const float*)d_in[9];
  const float* bh   = (const float*)d_in[10];
  const float* Wmu  = (const float*)d_in[11];
  const float* bmu  = (const float*)d_in[12];
  const float* Wsig = (const float*)d_in[13];
  const float* bsig = (const float*)d_in[14];
  float* out = (float*)d_out;

  char* ws = (char*)d_ws;
  __hip_bfloat16* latent = (__hip_bfloat16*)ws;                  // 16,777,216 B
  float* zh  = (float*)(ws + 16777216);                           //    262,144 B
  uint2* W1q = (uint2*)(ws + 17039360);                           //     65,536 B
  uint2* W2q = (uint2*)(ws + 17104896);                           //    131,072 B
  uint2* W3q = (uint2*)(ws + 17235968);                           //     65,536 B

  pack_kernel<<<dim3(128), dim3(256), 0, stream>>>(W1, W2, W3, W1q, W2q, W3q);
  zh_kernel<<<dim3(B_SZ), dim3(256), 0, stream>>>(z, Wh, bh, zh);
  ode_kernel<<<dim3(B_SZ), dim3(512), 0, stream>>>(
      x, z, x0, W1, b1, b2, b3, W1q, W2q, W3q, latent);
  decode_kernel<<<dim3(P_SZ / TT, B_SZ), dim3(256), 0, stream>>>(
      x, latent, zh, Wh, Wmu, bmu, Wsig, bsig, out);
}

// Round 3
// 976.814 us; speedup vs baseline: 1.1423x; 1.0185x over previous
//
#include <hip/hip_runtime.h>
#include <hip/hip_bf16.h>
#include <math.h>

// Problem dims (fixed by reference)
#define B_SZ 256
#define P_SZ 256
#define LD   128   // L_DIM (evolving part)
#define ZD   256   // Z_DIM
#define HD   256   // H_DIM
#define NSTEP 8            // RK4 macro steps over [0,1]
#define SPAN (P_SZ/NSTEP)  // fine intervals per macro step = 32
#define TT   16            // points per block in decode kernel

__device__ __forceinline__ float fast_tanh(float v) {
  float e = __expf(2.0f * fabsf(v));
  float r = 1.0f - 2.0f / (e + 1.0f);
  return copysignf(r, v);
}

__device__ __forceinline__ unsigned int bf_bits(float f) {
  unsigned int u = __float_as_uint(f);
  return (u + 0x7fffu + ((u >> 16) & 1u)) >> 16;   // RNE
}
__device__ __forceinline__ float bf_lo(unsigned int u) {
  return __uint_as_float(u << 16);
}
__device__ __forceinline__ float bf_hi(unsigned int u) {
  return __uint_as_float(u & 0xffff0000u);
}

// ---------------------------------------------------------------------------
// Prep: pack W1[0:128], W2, W3, Wh[1:129] into bf16 k-pair uint2 layout.
// W1q: (k>>2)*256+u, k in [0,128)  -> 8192 uint2
// W2q: (k>>2)*256+u, k in [0,256)  -> 16384 uint2
// W3q: (k>>2)*128+u, k in [0,256)  -> 8192 uint2
// Whq: (k>>2)*256+u, k in [0,128)  (Wh rows 1+k) -> 8192 uint2
// ---------------------------------------------------------------------------
__global__ __launch_bounds__(256) void pack_kernel(
    const float* __restrict__ W1, const float* __restrict__ W2,
    const float* __restrict__ W3, const float* __restrict__ Wh,
    uint2* __restrict__ W1q, uint2* __restrict__ W2q,
    uint2* __restrict__ W3q, uint2* __restrict__ Whq)
{
  int idx = blockIdx.x * 256 + threadIdx.x;
  if (idx < 8192) {
    int r = idx >> 8, u = idx & 255, k = r * 4;
    uint2 o;
    o.x = bf_bits(W1[(k + 0) * HD + u]) | (bf_bits(W1[(k + 1) * HD + u]) << 16);
    o.y = bf_bits(W1[(k + 2) * HD + u]) | (bf_bits(W1[(k + 3) * HD + u]) << 16);
    W1q[idx] = o;
  } else if (idx < 24576) {
    int i = idx - 8192;
    int r = i >> 8, u = i & 255, k = r * 4;
    uint2 o;
    o.x = bf_bits(W2[(k + 0) * HD + u]) | (bf_bits(W2[(k + 1) * HD + u]) << 16);
    o.y = bf_bits(W2[(k + 2) * HD + u]) | (bf_bits(W2[(k + 3) * HD + u]) << 16);
    W2q[i] = o;
  } else if (idx < 32768) {
    int i = idx - 24576;
    int r = i >> 7, u = i & 127, k = r * 4;
    uint2 o;
    o.x = bf_bits(W3[(k + 0) * LD + u]) | (bf_bits(W3[(k + 1) * LD + u]) << 16);
    o.y = bf_bits(W3[(k + 2) * LD + u]) | (bf_bits(W3[(k + 3) * LD + u]) << 16);
    W3q[i] = o;
  } else {
    int i = idx - 32768;
    int r = i >> 8, u = i & 255, k = r * 4;
    uint2 o;
    o.x = bf_bits(Wh[(1 + k) * HD + u]) | (bf_bits(Wh[(2 + k) * HD + u]) << 16);
    o.y = bf_bits(Wh[(3 + k) * HD + u]) | (bf_bits(Wh[(4 + k) * HD + u]) << 16);
    Whq[i] = o;
  }
}

// ---------------------------------------------------------------------------
// Kernel 1: one batch row per block, 512 threads, REGISTER-RESIDENT weights
// (bf16 packed, 128 VGPRs/thread; each thread owns a fixed weight slice).
// RK4 + cubic-Hermite dense output -> latent (bf16).
// ---------------------------------------------------------------------------
__global__ __launch_bounds__(512, 2) void ode_kernel(
    const float* __restrict__ x, const float* __restrict__ z,
    const float* __restrict__ x0,
    const float* __restrict__ W1, const float* __restrict__ b1,
    const float* __restrict__ b2, const float* __restrict__ b3,
    const uint2* __restrict__ W1q, const uint2* __restrict__ W2q,
    const uint2* __restrict__ W3q,
    __hip_bfloat16* __restrict__ latent)
{
  __shared__ float times[P_SZ + 1];
  __shared__ float vL[LD], vNew[LD], vin[LD], zf[LD];
  __shared__ float kb0[LD], kb1[LD], kb2[LD], kb3[LD];
  __shared__ float c1[HD], h1s[HD], h2s[HD];
  __shared__ float part[4][HD];

  const int tid = threadIdx.x;
  const int b   = blockIdx.x;
  const int u8  = tid & 255;   // hidden-unit index (layers 1/2)
  const int h2i = tid >> 8;    // split-K half (layers 1/2)
  const int u7  = tid & 127;   // output index (layer 3)
  const int s4  = tid >> 7;    // split-K quarter (layer 3)

  // ---- load this thread's weight slice into registers (once) ----
  uint2 rw1[16], rw2[32], rw3[16];
#pragma unroll
  for (int i = 0; i < 16; i++) rw1[i] = W1q[(h2i * 16 + i) * HD + u8];
#pragma unroll
  for (int i = 0; i < 32; i++) rw2[i] = W2q[(h2i * 32 + i) * HD + u8];
#pragma unroll
  for (int i = 0; i < 16; i++) rw3[i] = W3q[(s4 * 16 + i) * LD + u7];

  const float b2r = b2[u8];
  const float b3r = b3[u7];
  const float w1t = W1[ZD * HD + u8];   // W1 time row (fp32)

  for (int m = tid; m <= P_SZ; m += 512) times[m] = (m == 0) ? x0[0] : x[m - 1];
  if (tid < LD) {
    vL[tid] = z[b * ZD + tid];
    zf[tid] = z[b * ZD + LD + tid];
    kb0[tid] = 0.f;
  }
  __syncthreads();

  // c1[u] = b1[u] + zf . W1[128..255][u]  (fp32, once per block)
  {
    float a0 = 0.f, a1 = 0.f, a2 = 0.f, a3 = 0.f;
    int kb = h2i * 64;
#pragma unroll 4
    for (int k = kb; k < kb + 64; k += 4) {
      float4 zv = *(const float4*)&zf[k];
      a0 += zv.x * W1[(LD + k + 0) * HD + u8];
      a1 += zv.y * W1[(LD + k + 1) * HD + u8];
      a2 += zv.z * W1[(LD + k + 2) * HD + u8];
      a3 += zv.w * W1[(LD + k + 3) * HD + u8];
    }
    part[h2i][u8] = (a0 + a1) + (a2 + a3);
    __syncthreads();
    if (tid < HD) c1[tid] = b1[tid] + part[0][tid] + part[1][tid];
    __syncthreads();
  }

  // kout = f_L(t, vsrc + c*kin)
  auto eval_f = [&](float t, float* vsrc, float* kin, float c, float* kout) {
    if (tid < LD) vin[tid] = vsrc[tid] + c * kin[tid];
    __syncthreads();
    // layer 1 (K = 64 per half from registers; zf+b1 folded into c1; + time)
    {
      float a0 = 0.f, a1 = 0.f, a2 = 0.f, a3 = 0.f;
#pragma unroll
      for (int i = 0; i < 16; i++) {
        float4 vv = *(const float4*)&vin[h2i * 64 + i * 4];
        uint2 w = rw1[i];
        a0 += vv.x * bf_lo(w.x); a1 += vv.y * bf_hi(w.x);
        a2 += vv.z * bf_lo(w.y); a3 += vv.w * bf_hi(w.y);
      }
      float acc = (a0 + a1) + (a2 + a3);
      acc += (h2i == 0) ? c1[u8] : t * w1t;
      part[h2i][u8] = acc;
    }
    __syncthreads();
    if (tid < HD) h1s[tid] = fast_tanh(part[0][tid] + part[1][tid]);
    __syncthreads();
    // layer 2 (K = 128 per half from registers)
    {
      float a0 = 0.f, a1 = 0.f, a2 = 0.f, a3 = 0.f;
#pragma unroll
      for (int i = 0; i < 32; i++) {
        float4 hv = *(const float4*)&h1s[h2i * 128 + i * 4];
        uint2 w = rw2[i];
        a0 += hv.x * bf_lo(w.x); a1 += hv.y * bf_hi(w.x);
        a2 += hv.z * bf_lo(w.y); a3 += hv.w * bf_hi(w.y);
      }
      part[h2i][u8] = (a0 + a1) + (a2 + a3);
    }
    __syncthreads();
    if (tid < HD) h2s[tid] = fast_tanh(part[0][tid] + part[1][tid] + b2r);
    __syncthreads();
    // layer 3 (K = 64 per quarter from registers)
    {
      float a0 = 0.f, a1 = 0.f, a2 = 0.f, a3 = 0.f;
#pragma unroll
      for (int i = 0; i < 16; i++) {
        float4 hv = *(const float4*)&h2s[s4 * 64 + i * 4];
        uint2 w = rw3[i];
        a0 += hv.x * bf_lo(w.x); a1 += hv.y * bf_hi(w.x);
        a2 += hv.z * bf_lo(w.y); a3 += hv.w * bf_hi(w.y);
      }
      part[s4][u7] = (a0 + a1) + (a2 + a3);
    }
    __syncthreads();
    if (tid < LD)
      kout[tid] = b3r + part[0][tid] + part[1][tid] + part[2][tid] + part[3][tid];
    __syncthreads();
  };

  eval_f(times[0], vL, kb0, 0.f, kb0);   // k1 at t=0 (kb0 zero-initialized)

  for (int n = 0; n < NSTEP; n++) {
    float t0 = times[n * SPAN], t1 = times[(n + 1) * SPAN];
    float H = t1 - t0, tm = t0 + 0.5f * H;
    eval_f(tm, vL, kb0, 0.5f * H, kb1);   // k2
    eval_f(tm, vL, kb1, 0.5f * H, kb2);   // k3
    eval_f(t1, vL, kb2, H,        kb3);   // k4
    if (tid < LD)
      vNew[tid] = vL[tid] + (H / 6.0f) *
          (kb0[tid] + 2.f * kb1[tid] + 2.f * kb2[tid] + kb3[tid]);
    __syncthreads();
    eval_f(t1, vNew, kb0, 0.f, kb1);      // f at t1 (Hermite right slope)

    float invH = 1.0f / H;
    for (int idx = tid; idx < SPAN * LD; idx += 512) {
      int m_i = idx >> 7, k = idx & (LD - 1);
      int m = n * SPAN + 1 + m_i;
      float s  = (times[m] - t0) * invH;
      float s2 = s * s, s3 = s2 * s;
      float h00 = 2.f * s3 - 3.f * s2 + 1.f;
      float h10 = s3 - 2.f * s2 + s;
      float h01 = 3.f * s2 - 2.f * s3;
      float h11 = s3 - s2;
      float val = h00 * vL[k] + (h10 * H) * kb0[k]
                + h01 * vNew[k] + (h11 * H) * kb1[k];
      latent[((size_t)b * P_SZ + (m - 1)) * LD + k] = __float2bfloat16(val);
    }
    __syncthreads();
    if (tid < LD) { vL[tid] = vNew[tid]; kb0[tid] = kb1[tid]; }
    __syncthreads();
  }
}

// ---------------------------------------------------------------------------
// Kernel 2: zh[b][j] = bh[j] + sum_k z[b][128+k] * Wh[(129+k)][j]
// ---------------------------------------------------------------------------
__global__ __launch_bounds__(256) void zh_kernel(
    const float* __restrict__ z, const float* __restrict__ Wh,
    const float* __restrict__ bh, float* __restrict__ zh)
{
  const int b = blockIdx.x, j = threadIdx.x;
  __shared__ float zr[LD];
  if (j < LD) zr[j] = z[b * ZD + LD + j];
  __syncthreads();
  float acc = bh[j];
#pragma unroll 8
  for (int k = 0; k < LD; k += 4) {
    float4 zv = *(const float4*)&zr[k];
    acc += zv.x * Wh[(LD + 1 + k) * HD + j] + zv.y * Wh[(LD + 2 + k) * HD + j]
         + zv.z * Wh[(LD + 3 + k) * HD + j] + zv.w * Wh[(LD + 4 + k) * HD + j];
  }
  zh[b * HD + j] = acc;
}

// ---------------------------------------------------------------------------
// Kernel 3: decode. bf16-packed Wh rows 1..128; wave-local reductions.
// ---------------------------------------------------------------------------
__global__ __launch_bounds__(256) void decode_kernel(
    const float* __restrict__ x, const __hip_bfloat16* __restrict__ latent,
    const float* __restrict__ zh, const float* __restrict__ Wh,
    const uint2* __restrict__ Whq,
    const float* __restrict__ Wmu, const float* __restrict__ bmu,
    const float* __restrict__ Wsig, const float* __restrict__ bsig,
    float* __restrict__ out)
{
  const int b  = blockIdx.y;
  const int p0 = blockIdx.x * TT;
  const int j  = threadIdx.x;
  __shared__ float lat[TT][LD];
  __shared__ float hid[TT][HD];
  __shared__ float xv[TT];
  __shared__ float zhs[HD];

  // latent bf16 -> LDS fp32 (dword = 2 bf16)
  {
    const unsigned int* lp = (const unsigned int*)latent;
    for (int idx = j; idx < TT * LD / 2; idx += 256) {
      int t = idx >> 6, kk = (idx & 63) * 2;
      unsigned int ld2 = lp[((size_t)b * P_SZ + p0 + t) * (LD / 2) + (idx & 63)];
      lat[t][kk]     = __uint_as_float(ld2 << 16);
      lat[t][kk + 1] = __uint_as_float(ld2 & 0xffff0000u);
    }
  }
  if (j < TT) xv[j] = x[b * P_SZ + p0 + j];
  zhs[j] = zh[b * HD + j];
  __syncthreads();

  // phase 1: hidden[t][j] = relu(x*Wh0 + latent@Wh[1:129] + zh)
  float acc[TT];
  float wh0 = Wh[j];
  float zhj = zhs[j];
#pragma unroll
  for (int t = 0; t < TT; t++) acc[t] = zhj + xv[t] * wh0;

  for (int k = 0; k < LD; k += 4) {
    uint2 w = Whq[(k >> 2) * HD + j];
    float w0 = bf_lo(w.x), w1 = bf_hi(w.x), w2 = bf_lo(w.y), w3 = bf_hi(w.y);
#pragma unroll
    for (int t = 0; t < TT; t++) {
      float4 lv = *(const float4*)&lat[t][k];
      acc[t] += lv.x * w0 + lv.y * w1 + lv.z * w2 + lv.w * w3;
    }
  }
#pragma unroll
  for (int t = 0; t < TT; t++) hid[t][j] = fmaxf(acc[t], 0.f);
  __syncthreads();

  // phase 2: each wave handles 4 points; lanewise partial over 384-dim, shfl reduce
  const int w = j >> 6, l = j & 63;
  float wmu_h[4], wsg_h[4], wmu_l[2], wsg_l[2];
#pragma unroll
  for (int c = 0; c < 4; c++) {
    wmu_h[c] = Wmu[LD + l + 64 * c];
    wsg_h[c] = Wsig[LD + l + 64 * c];
  }
#pragma unroll
  for (int c = 0; c < 2; c++) {
    wmu_l[c] = Wmu[l + 64 * c];
    wsg_l[c] = Wsig[l + 64 * c];
  }
  const float bmu0 = bmu[0], bsg0 = bsig[0];

#pragma unroll
  for (int tt = 0; tt < 4; tt++) {
    int t = w * 4 + tt;
    float m = 0.f, sg = 0.f;
#pragma unroll
    for (int c = 0; c < 4; c++) {
      float hv = hid[t][l + 64 * c];
      m += hv * wmu_h[c]; sg += hv * wsg_h[c];
    }
#pragma unroll
    for (int c = 0; c < 2; c++) {
      float lv = lat[t][l + 64 * c];
      m += lv * wmu_l[c]; sg += lv * wsg_l[c];
    }
#pragma unroll
    for (int off = 32; off > 0; off >>= 1) {
      m  += __shfl_down(m, off);
      sg += __shfl_down(sg, off);
    }
    if (l == 0) {
      out[(size_t)b * P_SZ + p0 + t] = m + bmu0;
      float sv = sg + bsg0;
      float sp = (sv > 20.f) ? sv : log1pf(__expf(sv));
      out[(size_t)B_SZ * P_SZ + b * P_SZ + p0 + t] = 0.1f + 0.9f * sp;
    }
  }
}

// ---------------------------------------------------------------------------
extern "C" void kernel_launch(void* const* d_in, const int* in_sizes, int n_in,
                              void* d_out, int out_size, void* d_ws, size_t ws_size,
                              hipStream_t stream) {
  const float* x    = (const float*)d_in[0];
  const float* z    = (const float*)d_in[1];
  const float* x0   = (const float*)d_in[2];
  const float* W1   = (const float*)d_in[3];
  const float* b1   = (const float*)d_in[4];
  const float* W2   = (const float*)d_in[5];
  const float* b2   = (const float*)d_in[6];
  const float* W3   = (const float*)d_in[7];
  const float* b3   = (const float*)d_in[8];
  const float* Wh   = (const float*)d_in[9];
  const float* bh   = (const float*)d_in[10];
  const float* Wmu  = (const float*)d_in[11];
  const float* bmu  = (const float*)d_in[12];
  const float* Wsig = (const float*)d_in[13];
  const float* bsig = (const float*)d_in[14];
  float* out = (float*)d_out;

  char* ws = (char*)d_ws;
  __hip_bfloat16* latent = (__hip_bfloat16*)ws;                  // 16,777,216 B
  float* zh  = (float*)(ws + 16777216);                           //    262,144 B
  uint2* W1q = (uint2*)(ws + 17039360);                           //     65,536 B
  uint2* W2q = (uint2*)(ws + 17104896);                           //    131,072 B
  uint2* W3q = (uint2*)(ws + 17235968);                           //     65,536 B
  uint2* Whq = (uint2*)(ws + 17301504);                           //     65,536 B

  pack_kernel<<<dim3(160), dim3(256), 0, stream>>>(W1, W2, W3, Wh,
                                                   W1q, W2q, W3q, Whq);
  zh_kernel<<<dim3(B_SZ), dim3(256), 0, stream>>>(z, Wh, bh, zh);
  ode_kernel<<<dim3(B_SZ), dim3(512), 0, stream>>>(
      x, z, x0, W1, b1, b2, b3, W1q, W2q, W3q, latent);
  decode_kernel<<<dim3(P_SZ / TT, B_SZ), dim3(256), 0, stream>>>(
      x, latent, zh, Wh, Whq, Wmu, bmu, Wsig, bsig, out);
}